// Round 8
// baseline (135.770 us; speedup 1.0000x reference)
//
#include <hip/hip_runtime.h>

// Problem constants (match reference)
#define NX_ 64
#define NY_ 64
#define NBINS 128
#define NSUB 10
#define NV (NSUB * NBINS)      // 1280
#define PADL NV                // 1280
#define ROWLEN (NV + 2 * PADL) // 3840
#define BATCH 32
#define NROWS (NY_ * NX_)          // 4096
#define CELLS (BATCH * NY_ * NX_)  // 131072
#define CAP 128                    // bucket capacity per row (avg 32, max ~77 expected)
#define TABN (BATCH * NBINS)       // 4096

// Pass 1: bin each cell by its (yi, xi) table row. cnt pre-zeroed by memsetAsync.
// Overflow (statistically never: avg 32/row vs CAP 128) serves the cell directly,
// computing the v-index arithmetic inline (bit-identical f32 expression).
__global__ __launch_bounds__(256) void bin_kernel(
    const float* __restrict__ cur_pos,   // (B,64,64,2)
    const float* __restrict__ deltas,    // (B,3)
    const int* __restrict__ is_cam,
    const float* __restrict__ voxel,     // for overflow slow path
    int* __restrict__ cnt,               // (4096) zeroed via memsetAsync
    unsigned* __restrict__ bucket,       // (4096, CAP)
    float* __restrict__ out,
    float vr_f, float vbase_f)
{
    int cell = blockIdx.x * 256 + threadIdx.x;
    int b = cell >> 12;  // 4096 cells per batch

    float sign = (is_cam[0] != 0) ? 1.0f : -1.0f;
    float2 p = ((const float2*)cur_pos)[cell];
    float dx = deltas[b * 3 + 0];
    float dy = deltas[b * 3 + 1];

    float xs = fminf(fmaxf(p.x + sign * dx, -1.0f), 1.0f);
    float ys = fminf(fmaxf(p.y + sign * dy, -1.0f), 1.0f);
    int xi = (int)(32.0f * (xs + 1.0f));
    int yi = (int)(32.0f * (ys + 1.0f));
    xi = min(max(xi, 0), NX_ - 1);
    yi = min(max(yi, 0), NY_ - 1);
    int r = yi * NX_ + xi;

    int pos = atomicAdd(&cnt[r], 1);
    if (pos < CAP) {
        bucket[r * CAP + pos] = (unsigned)cell;
    } else {
        // slow path: serve this cell directly from global (correctness net)
        const float* __restrict__ row = voxel + (size_t)r * ROWLEN;
        float* __restrict__ o = out + (size_t)cell * NBINS;
        float dv = deltas[b * 3 + 2];
        float step = vr_f / 127.0f;
        for (int k = 0; k < NBINS; ++k) {
            float xl = (k == NBINS - 1) ? vr_f : (float)k * step;
            int t = PADL + (int)((-dv + xl) / vbase_f);
            o[k] = row[t];
        }
    }
}

// Pass 2: one block per table row. Build the (b,k)->v_idx table in LDS
// (cheap arithmetic, removes global tab round-trip from the serve path),
// stage the union span [lo4..end4) into LDS once (float4), then serve every
// cell binned to this row from LDS. 512 threads = 16 groups of 32 lanes;
// lane handles k = lane + 32j -> LDS span stride ~10 floats across lanes
// (~4-way bank aliasing, near-free); tab reads consecutive (conflict-free);
// stores stride-1 coalesced.
__global__ __launch_bounds__(512) void row_gather_kernel(
    const float* __restrict__ voxel,     // (64,64,3840)
    const float* __restrict__ deltas,    // (B,3)
    const int* __restrict__ cnt,         // (4096)
    const unsigned* __restrict__ bucket, // (4096, CAP)
    float* __restrict__ out,             // (B,64,64,128)
    float vr_f, float vbase_f)
{
    int r = blockIdx.x;
    int n = cnt[r];
    if (n == 0) return;
    if (n > CAP) n = CAP;

    __shared__ __align__(16) float span[ROWLEN];  // worst-case full row, 15 KB
    __shared__ int tabl[TABN];                    // 16 KB
    __shared__ unsigned s_cells[CAP];
    __shared__ int s_lo, s_len;

    int tid = threadIdx.x;

    // stage this row's cell list
    if (tid < n) s_cells[tid] = bucket[r * CAP + tid];

    // build v-idx table in LDS: bit-parity with reference
    // (f32 linspace w/ endpoint fixup; IEEE f32 div; trunc toward zero)
    float step = vr_f / 127.0f;
    #pragma unroll
    for (int i = tid; i < TABN; i += 512) {
        int b = i >> 7;
        int k = i & (NBINS - 1);
        float dv = deltas[b * 3 + 2];
        float xl = (k == NBINS - 1) ? vr_f : (float)k * step;
        tabl[i] = PADL + (int)((-dv + xl) / vbase_f);
    }
    __syncthreads();

    // lo = min_b tab[b][0], hi = max_b tab[b][127]  (tab monotone in k)
    if (tid < 64) {
        int bb = tid & 31;
        int lo = tabl[bb * 128];
        int hi = tabl[bb * 128 + 127];
        #pragma unroll
        for (int m = 16; m >= 1; m >>= 1) {
            lo = min(lo, __shfl_xor(lo, m));
            hi = max(hi, __shfl_xor(hi, m));
        }
        if (tid == 0) {
            lo = max(lo, 0);
            hi = min(hi, ROWLEN - 1);
            s_lo = lo;
            s_len = hi - lo + 1;
        }
    }
    __syncthreads();

    // float4 staging of [lo4, end4) — row base is 16B-aligned (ROWLEN%4==0).
    int lo4 = s_lo & ~3;
    int end4 = (s_lo + s_len + 3) & ~3;
    if (end4 > ROWLEN) end4 = ROWLEN;
    int nvec = (end4 - lo4) >> 2;
    const float4* __restrict__ row4 =
        (const float4*)(voxel + (size_t)r * ROWLEN) + (lo4 >> 2);
    float4* span4 = (float4*)span;
    for (int i = tid; i < nvec; i += 512) span4[i] = row4[i];
    __syncthreads();

    int g = tid >> 5, lane = tid & 31;
    for (int ci = g; ci < n; ci += 16) {
        unsigned cell = s_cells[ci];
        int b = (int)(cell >> 12);
        const int* t = tabl + b * NBINS;
        int i0 = t[lane]      - lo4;
        int i1 = t[lane + 32] - lo4;
        int i2 = t[lane + 64] - lo4;
        int i3 = t[lane + 96] - lo4;
        float v0 = span[i0], v1 = span[i1], v2 = span[i2], v3 = span[i3];
        float* __restrict__ o = out + (size_t)cell * NBINS;
        o[lane]      = v0;
        o[lane + 32] = v1;
        o[lane + 64] = v2;
        o[lane + 96] = v3;
    }
}

extern "C" void kernel_launch(void* const* d_in, const int* in_sizes, int n_in,
                              void* d_out, int out_size, void* d_ws, size_t ws_size,
                              hipStream_t stream) {
    const float* cur_pos = (const float*)d_in[0];
    const float* deltas  = (const float*)d_in[1];
    const float* voxel   = (const float*)d_in[2];
    const int*   is_cam  = (const int*)d_in[3];
    float* out = (float*)d_out;

    // d_ws layout: cnt (16 KB) | bucket (2 MB)
    int* cnt = (int*)d_ws;
    unsigned* bucket = (unsigned*)(cnt + NROWS);

    const double vr_d = ((3.0e8 * 128.0) * 32e-12 / 2.0) * ((3.0e8 * 128.0) * 32e-12 / 2.0);
    const float vr_f = (float)vr_d;
    const float vbase_f = (float)(vr_d / (double)NV);

    hipMemsetAsync(cnt, 0, NROWS * sizeof(int), stream);

    hipLaunchKernelGGL(bin_kernel, dim3(CELLS / 256), dim3(256), 0, stream,
                       cur_pos, deltas, is_cam, voxel, cnt, bucket, out,
                       vr_f, vbase_f);

    hipLaunchKernelGGL(row_gather_kernel, dim3(NROWS), dim3(512), 0, stream,
                       voxel, deltas, cnt, bucket, out, vr_f, vbase_f);
}